// Round 5
// baseline (543.086 us; speedup 1.0000x reference)
//
#include <hip/hip_runtime.h>

// VectorQuantizer: x [32,64,64,64] f32, emb [512,64] f32 -> out [32,64,64,64] f32
// out[b,:,h,w] = emb[argmin_k dists], reproducing numpy FLOAT32 bit semantics
// (verified absmax==0 in R2-R4):
//   dists[k] = fl( fl(x_sq + e_sq[k]) - fl(2*dot[k]) )
//   dot      = sequential-c FMA chain (BLAS order)
//   x_sq/e_sq= numpy pairwise-8 sums; argmin: ascending k, strict <.
//
// R5 restructure: R2-R4 all showed ~2.4x VALU inflation because the backend
// refuses to keep xr[64] resident (VGPR squeezed to 40-52; launch_bounds,
// waves_per_eu, asm pins all defeated). Fix = remove the 64-float live range
// from the source: x tile lives in LDS (stride 68: 16B-aligned b128, even
// bank coverage), inner loop holds only one float4 of x + 8 accumulators
// (~30 VGPRs). emb stays on the scalar (s_load) path; e_sq precomputed to
// d_ws by a prep kernel. K split 4-ways across the block's waves -> 8192
// waves, 8 blocks/CU (156 KB LDS), VALU-bound at the 16.4K-cyc/wave floor.

#define KNUM   512
#define CDIM   64
#define PPB    64                 // pixels per block
#define KSPLIT 4                  // k-quarters (one per wave)
#define KPT    (KNUM / KSPLIT)    // 128 codes per thread
#define XPAD   68                 // x-tile row stride in floats

__global__ __launch_bounds__(256) void vq_prep(const float* __restrict__ emb,
                                               float* __restrict__ e_sq)
{
    const int k = blockIdx.x * 256 + threadIdx.x;
    if (k < KNUM) {
        const float* e = emb + k * CDIM;
        float r[8];
        #pragma unroll
        for (int j = 0; j < 8; ++j) r[j] = __fmul_rn(e[j], e[j]);
        #pragma unroll
        for (int i = 8; i < CDIM; i += 8)
            #pragma unroll
            for (int j = 0; j < 8; ++j)
                r[j] = __fadd_rn(r[j], __fmul_rn(e[i + j], e[i + j]));
        e_sq[k] = __fadd_rn(
            __fadd_rn(__fadd_rn(r[0], r[1]), __fadd_rn(r[2], r[3])),
            __fadd_rn(__fadd_rn(r[4], r[5]), __fadd_rn(r[6], r[7])));
    }
}

__global__ __launch_bounds__(256) void vq_main(const float* __restrict__ x,
                                               const float* __restrict__ emb,
                                               const float* __restrict__ e_sq,
                                               float* __restrict__ out)
{
    __shared__ float xt[PPB][XPAD];          // 17408 B
    __shared__ float rbest[KSPLIT][PPB];     //  1024 B
    __shared__ int   ridx [KSPLIT][PPB];     //  1024 B

    const int tid  = threadIdx.x;
    const int p    = tid & 63;               // pixel lane
    const int q    = tid >> 6;               // wave id = k-quarter = c-quarter
    const int pix0 = blockIdx.x * PPB;
    const int b    = pix0 >> 12;             // H*W = 4096
    const int hw0  = pix0 & 4095;
    const float* xb = x + (((size_t)b * CDIM) << 12) + hw0;

    // stage x tile: wave q loads channels c = q + 4i, lanes = consecutive hw
    #pragma unroll
    for (int i = 0; i < 16; ++i) {
        const int c = q + 4 * i;
        xt[p][c] = xb[((size_t)c << 12) + p];   // 256 B coalesced per inst
    }
    __syncthreads();

    // x_sq, numpy pairwise-8 semantics (redundant across the 4 quarter-threads)
    float xs;
    {
        const float* xr = xt[p];
        float r[8];
        #pragma unroll
        for (int j = 0; j < 8; ++j) r[j] = __fmul_rn(xr[j], xr[j]);
        #pragma unroll
        for (int i = 8; i < CDIM; i += 8)
            #pragma unroll
            for (int j = 0; j < 8; ++j)
                r[j] = __fadd_rn(r[j], __fmul_rn(xr[i + j], xr[i + j]));
        xs = __fadd_rn(
            __fadd_rn(__fadd_rn(r[0], r[1]), __fadd_rn(r[2], r[3])),
            __fadd_rn(__fadd_rn(r[4], r[5]), __fadd_rn(r[6], r[7])));
    }

    // scan this quarter's 128 codes, 8 rows per iteration
    const int k0 = q * KPT;
    float best = 3.4e38f;
    int bidx = k0;
    #pragma unroll 1
    for (int k = k0; k < k0 + KPT; k += 8) {
        const float* e = emb + (size_t)k * CDIM;     // uniform -> s_load
        float d[8];
        #pragma unroll
        for (int r = 0; r < 8; ++r) d[r] = 0.f;
        #pragma unroll
        for (int c4 = 0; c4 < 16; ++c4) {
            const float4 xv = *(const float4*)&xt[p][c4 * 4];  // ds_read_b128
            #pragma unroll
            for (int j = 0; j < 4; ++j) {
                const float xc = (j == 0) ? xv.x : (j == 1) ? xv.y
                               : (j == 2) ? xv.z : xv.w;
                #pragma unroll
                for (int r = 0; r < 8; ++r)          // c = 4*c4+j ascending per row
                    d[r] = fmaf(xc, e[r * CDIM + c4 * 4 + j], d[r]);
            }
        }
        #pragma unroll
        for (int r = 0; r < 8; ++r) {                // ascending r, strict <
            const float s = __fsub_rn(__fadd_rn(xs, e_sq[k + r]),
                                      __fmul_rn(2.0f, d[r]));
            if (s < best) { best = s; bidx = k + r; }
        }
    }

    rbest[q][p] = best;
    ridx [q][p] = bidx;
    __syncthreads();

    // combine quarters ascending, strict < => global first-occurrence argmin
    float wb = rbest[0][p];
    int   wi = ridx [0][p];
    #pragma unroll
    for (int qq = 1; qq < KSPLIT; ++qq) {
        const float bq = rbest[qq][p];
        const int   iq = ridx [qq][p];
        if (bq < wb) { wb = bq; wi = iq; }
    }

    // gather: each quarter-thread writes its 16 channels (bit-exact emb copy)
    const float* er = emb + ((size_t)wi * CDIM) + q * 16;   // 64B-aligned
    const float4 v0 = *(const float4*)(er);
    const float4 v1 = *(const float4*)(er + 4);
    const float4 v2 = *(const float4*)(er + 8);
    const float4 v3 = *(const float4*)(er + 12);
    float* ob = out + (((size_t)b * CDIM) << 12) + (((size_t)(q * 16)) << 12) + hw0 + p;
    ob[(size_t) 0 << 12] = v0.x;  ob[(size_t) 1 << 12] = v0.y;
    ob[(size_t) 2 << 12] = v0.z;  ob[(size_t) 3 << 12] = v0.w;
    ob[(size_t) 4 << 12] = v1.x;  ob[(size_t) 5 << 12] = v1.y;
    ob[(size_t) 6 << 12] = v1.z;  ob[(size_t) 7 << 12] = v1.w;
    ob[(size_t) 8 << 12] = v2.x;  ob[(size_t) 9 << 12] = v2.y;
    ob[(size_t)10 << 12] = v2.z;  ob[(size_t)11 << 12] = v2.w;
    ob[(size_t)12 << 12] = v3.x;  ob[(size_t)13 << 12] = v3.y;
    ob[(size_t)14 << 12] = v3.z;  ob[(size_t)15 << 12] = v3.w;
}

extern "C" void kernel_launch(void* const* d_in, const int* in_sizes, int n_in,
                              void* d_out, int out_size, void* d_ws, size_t ws_size,
                              hipStream_t stream)
{
    const float* x   = (const float*)d_in[0];
    const float* emb = (const float*)d_in[1];
    float* out  = (float*)d_out;
    float* e_sq = (float*)d_ws;                    // 512 floats of scratch

    hipLaunchKernelGGL(vq_prep, dim3(2), dim3(256), 0, stream, emb, e_sq);
    const int nblocks = (32 * 64 * 64) / PPB;      // 2048
    hipLaunchKernelGGL(vq_main, dim3(nblocks), dim3(256), 0, stream,
                       x, emb, e_sq, out);
}

// Round 6
// 244.946 us; speedup vs baseline: 2.2172x; 2.2172x over previous
//
#include <hip/hip_runtime.h>

// VectorQuantizer: x [32,64,64,64] f32, emb [512,64] f32 -> out [32,64,64,64] f32
// out[b,:,h,w] = emb[argmin_k dists], reproducing numpy FLOAT32 bit semantics
// (verified absmax==0 in R2-R5):
//   dists[k] = fl( fl(x_sq + e_sq[k]) - fl(2*dot[k]) )
//   dot      = sequential-c FMA chain; x_sq/e_sq = numpy pairwise-8 sums;
//   argmin: ascending k, strict <.
//
// R6 = R5 structure (x in LDS, small per-thread state) + two fixes:
//  1. q = readfirstlane(tid>>6): R5's plain tid>>6 lost the emb s_load path
//     (SGPR 112->32, per-lane VMEM loads of emb, VALUBusy 25%). With q
//     uniform, emb/e_sq addresses are scalar -> s_load broadcast, FMA reads
//     the emb operand from SGPR for free.
//  2. k-tile 16 (d[16] accumulators): accumulators are non-rematerializable
//     state (unlike R2-R4's x array, which the allocator kept re-loading),
//     and each ds_read_b128 of x now feeds 64 FMAs -> LDS pipe ~29% of VALU.
// Budget: 8192 waves (8/SIMD; 19.5 KB LDS -> 8 blocks/CU), 8192 FMA-inst/wave
// x 2 cyc -> 131K cyc/SIMD = 54.6 us VALU floor.

#define KNUM   512
#define CDIM   64
#define PPB    64                 // pixels per block
#define KSPLIT 4                  // k-quarters (one per wave)
#define KPT    (KNUM / KSPLIT)    // 128 codes per wave
#define TK     16                 // codes per k-tile
#define XPAD   68                 // x-tile row stride (even 8x bank coverage for b128)

__global__ __launch_bounds__(256) void vq_prep(const float* __restrict__ emb,
                                               float* __restrict__ e_sq)
{
    const int k = blockIdx.x * 256 + threadIdx.x;
    if (k < KNUM) {
        const float* e = emb + k * CDIM;
        float r[8];
        #pragma unroll
        for (int j = 0; j < 8; ++j) r[j] = __fmul_rn(e[j], e[j]);
        #pragma unroll
        for (int i = 8; i < CDIM; i += 8)
            #pragma unroll
            for (int j = 0; j < 8; ++j)
                r[j] = __fadd_rn(r[j], __fmul_rn(e[i + j], e[i + j]));
        e_sq[k] = __fadd_rn(
            __fadd_rn(__fadd_rn(r[0], r[1]), __fadd_rn(r[2], r[3])),
            __fadd_rn(__fadd_rn(r[4], r[5]), __fadd_rn(r[6], r[7])));
    }
}

__global__ __launch_bounds__(256) void vq_main(const float* __restrict__ x,
                                               const float* __restrict__ emb,
                                               const float* __restrict__ e_sq,
                                               float* __restrict__ out)
{
    __shared__ float xt[PPB][XPAD];          // 17408 B
    __shared__ float rbest[KSPLIT][PPB];
    __shared__ int   ridx [KSPLIT][PPB];

    const int tid = threadIdx.x;
    const int p   = tid & 63;                                   // pixel lane
    const int q   = __builtin_amdgcn_readfirstlane(tid >> 6);   // wave id (UNIFORM)
    const int pix0 = blockIdx.x * PPB;
    const int b    = pix0 >> 12;             // H*W = 4096
    const int hw0  = pix0 & 4095;
    const float* xb = x + (((size_t)b * CDIM) << 12) + hw0;

    // stage x tile: 4 b128 chunks per thread; 4 coalesced dword loads each
    #pragma unroll
    for (int i = 0; i < 4; ++i) {
        const int c0 = 4 * (q + 4 * i);      // 0..60 step 4 across waves
        float4 v;
        v.x = xb[((size_t)(c0 + 0) << 12) + p];
        v.y = xb[((size_t)(c0 + 1) << 12) + p];
        v.z = xb[((size_t)(c0 + 2) << 12) + p];
        v.w = xb[((size_t)(c0 + 3) << 12) + p];
        *(float4*)&xt[p][c0] = v;            // ds_write_b128, even bank coverage
    }
    __syncthreads();

    // x_sq, numpy pairwise-8 semantics (r[j] accumulates elements 8i+j)
    float xs;
    {
        float r[8];
        {
            const float4 a = *(const float4*)&xt[p][0];
            const float4 c = *(const float4*)&xt[p][4];
            r[0] = __fmul_rn(a.x, a.x); r[1] = __fmul_rn(a.y, a.y);
            r[2] = __fmul_rn(a.z, a.z); r[3] = __fmul_rn(a.w, a.w);
            r[4] = __fmul_rn(c.x, c.x); r[5] = __fmul_rn(c.y, c.y);
            r[6] = __fmul_rn(c.z, c.z); r[7] = __fmul_rn(c.w, c.w);
        }
        #pragma unroll
        for (int i = 1; i < 8; ++i) {
            const float4 a = *(const float4*)&xt[p][8 * i];
            const float4 c = *(const float4*)&xt[p][8 * i + 4];
            r[0] = __fadd_rn(r[0], __fmul_rn(a.x, a.x));
            r[1] = __fadd_rn(r[1], __fmul_rn(a.y, a.y));
            r[2] = __fadd_rn(r[2], __fmul_rn(a.z, a.z));
            r[3] = __fadd_rn(r[3], __fmul_rn(a.w, a.w));
            r[4] = __fadd_rn(r[4], __fmul_rn(c.x, c.x));
            r[5] = __fadd_rn(r[5], __fmul_rn(c.y, c.y));
            r[6] = __fadd_rn(r[6], __fmul_rn(c.z, c.z));
            r[7] = __fadd_rn(r[7], __fmul_rn(c.w, c.w));
        }
        xs = __fadd_rn(
            __fadd_rn(__fadd_rn(r[0], r[1]), __fadd_rn(r[2], r[3])),
            __fadd_rn(__fadd_rn(r[4], r[5]), __fadd_rn(r[6], r[7])));
    }

    // scan this quarter's 128 codes, 16 rows per tile
    const int k0 = q * KPT;                  // uniform
    float best = 3.4e38f;
    int bidx = k0;
    #pragma unroll 1
    for (int kt = 0; kt < KPT; kt += TK) {
        const int k = k0 + kt;               // uniform
        const float* e = emb + (size_t)k * CDIM;   // scalar addr -> s_load
        float d[TK];
        #pragma unroll
        for (int r = 0; r < TK; ++r) d[r] = 0.f;
        #pragma unroll
        for (int c4 = 0; c4 < 16; ++c4) {
            const float4 xv = *(const float4*)&xt[p][4 * c4];  // ds_read_b128
            #pragma unroll
            for (int j = 0; j < 4; ++j) {    // c = 4*c4+j ascending per row
                const float xc = (j == 0) ? xv.x : (j == 1) ? xv.y
                               : (j == 2) ? xv.z : xv.w;
                #pragma unroll
                for (int r = 0; r < TK; ++r)
                    d[r] = fmaf(xc, e[r * CDIM + 4 * c4 + j], d[r]);
            }
        }
        #pragma unroll
        for (int r = 0; r < TK; ++r) {       // ascending r, strict <
            const float s = __fsub_rn(__fadd_rn(xs, e_sq[k + r]),
                                      __fmul_rn(2.0f, d[r]));
            if (s < best) { best = s; bidx = k + r; }
        }
    }

    rbest[q][p] = best;
    ridx [q][p] = bidx;
    __syncthreads();

    // combine quarters ascending, strict < => global first-occurrence argmin
    float wb = rbest[0][p];
    int   wi = ridx [0][p];
    #pragma unroll
    for (int qq = 1; qq < KSPLIT; ++qq) {
        const float bq = rbest[qq][p];
        const int   iq = ridx [qq][p];
        if (bq < wb) { wb = bq; wi = iq; }
    }

    // gather: each quarter-thread writes its 16 channels (bit-exact emb copy)
    const float* er = emb + ((size_t)wi * CDIM) + q * 16;
    const float4 v0 = *(const float4*)(er);
    const float4 v1 = *(const float4*)(er + 4);
    const float4 v2 = *(const float4*)(er + 8);
    const float4 v3 = *(const float4*)(er + 12);
    float* ob = out + (((size_t)b * CDIM) << 12) + (((size_t)(q * 16)) << 12) + hw0 + p;
    ob[(size_t) 0 << 12] = v0.x;  ob[(size_t) 1 << 12] = v0.y;
    ob[(size_t) 2 << 12] = v0.z;  ob[(size_t) 3 << 12] = v0.w;
    ob[(size_t) 4 << 12] = v1.x;  ob[(size_t) 5 << 12] = v1.y;
    ob[(size_t) 6 << 12] = v1.z;  ob[(size_t) 7 << 12] = v1.w;
    ob[(size_t) 8 << 12] = v2.x;  ob[(size_t) 9 << 12] = v2.y;
    ob[(size_t)10 << 12] = v2.z;  ob[(size_t)11 << 12] = v2.w;
    ob[(size_t)12 << 12] = v3.x;  ob[(size_t)13 << 12] = v3.y;
    ob[(size_t)14 << 12] = v3.z;  ob[(size_t)15 << 12] = v3.w;
}

extern "C" void kernel_launch(void* const* d_in, const int* in_sizes, int n_in,
                              void* d_out, int out_size, void* d_ws, size_t ws_size,
                              hipStream_t stream)
{
    const float* x   = (const float*)d_in[0];
    const float* emb = (const float*)d_in[1];
    float* out  = (float*)d_out;
    float* e_sq = (float*)d_ws;                    // 512 floats of scratch

    hipLaunchKernelGGL(vq_prep, dim3(2), dim3(256), 0, stream, emb, e_sq);
    const int nblocks = (32 * 64 * 64) / PPB;      // 2048
    hipLaunchKernelGGL(vq_main, dim3(nblocks), dim3(256), 0, stream,
                       x, emb, e_sq, out);
}